// Round 4
// baseline (116.700 us; speedup 1.0000x reference)
//
#include <hip/hip_runtime.h>
#include <math.h>
#include <stdint.h>

#define BB 256
#define TT 512
#define KK 20
#define START_TAG 18
#define STOP_TAG 19
#define NST 400
#define SEGSTRIDE 420        // 400 M + 20 col-exponents
#define WS_SEG_OFF 1024
#define TPW 12               // tasks per wave (5 lanes each, lanes 60-63 idle for compute)
#define NI 19                // global_load_lds instructions: ceil(1200 chunks / 64)

__device__ __forceinline__ float fexp2(float x){ float r; asm("v_exp_f32 %0, %1":"=v"(r):"v"(x)); return r; }
__device__ __forceinline__ float flog2(float x){ float r; asm("v_log_f32 %0, %1":"=v"(r):"v"(x)); return r; }

__device__ __forceinline__ void gll16(const void* g, void* l) {
    __builtin_amdgcn_global_load_lds(
        (const __attribute__((address_space(1))) void*)g,
        (__attribute__((address_space(3))) void*)l, 16, 0, 0);
}

// ============ pass 1: per-segment 20x20 matrix products ============
// 12 tasks/wave, 5 lanes/task, lane owns 4 columns of the running product.
// Features DMA'd global->LDS (16B gll) with chunk-rotation swizzle (k+g)%5 to
// spread the stride-400 task layout over banks; in-place exp2 pass (own rows);
// per-column pow2 renorm every 4 steps.
template<int SEGL, int SEGS>
__global__ __launch_bounds__(64,2) void seg_kernel2(
    const float* __restrict__ feats, const int* __restrict__ lengths,
    float* __restrict__ wseg)
{
    constexpr int TASKS2 = BB*SEGS;
    constexpr float LOG2E = 1.4426950408889634f;
    const int lane = threadIdx.x;

    __shared__ __align__(16) float E[TPW*NST];   // 19200 B, chunk-swizzled

    // ---- compute role ----
    int g = lane / 5;
    int p = lane - 5*g;
    const bool alive = (g < TPW);
    const int gc = alive ? g : (TPW-1);
    int traw = blockIdx.x*TPW + gc;
    const bool real = alive && (traw < TASKS2);
    const int task = (traw < TASKS2) ? traw : (TASKS2-1);
    const int b = task / SEGS;
    const int s = task - b*SEGS;
    const int seg0 = 1 + SEGL*s;
    const int len = lengths[b];
    int nv_ = len - seg0; nv_ = nv_ < 0 ? 0 : (nv_ > SEGL ? SEGL : nv_);

    int itmax = nv_;
    #pragma unroll
    for (int o = 32; o > 0; o >>= 1){ int t2 = __shfl_xor(itmax, o, 64); itmax = t2 > itmax ? t2 : itmax; }
    if (itmax == 0) return;

    // ---- gll role: per-lane source offsets for 19 DMA instrs ----
    uint32_t cur[NI], lim[NI];
    #pragma unroll
    for (int m = 0; m < NI; ++m){
        int n = 64*m + lane;
        int nc = (n < TPW*100) ? n : 0;
        int gm = nc / 100;
        int rem = nc - 100*gm;
        int rm = rem / 5;
        int kp = rem - 5*rm;          // stored slot
        int km = kp - (gm % 5); if (km < 0) km += 5;   // logical chunk
        int tk = blockIdx.x*TPW + gm; if (tk >= TASKS2) tk = TASKS2-1;
        int bm = tk / SEGS, sm = tk - bm*SEGS;
        uint32_t base = ((uint32_t)bm*TT*NST + (uint32_t)(rm*20 + km*4)) * 4u;
        cur[m] = base + (uint32_t)(1 + SEGL*sm) * 1600u;
        lim[m] = base + 511u * 1600u;
    }

    const char* fB = (const char*)feats;
    // prologue: DMA E for it=0
    #pragma unroll
    for (int m = 0; m < NI; ++m){
        if (m < NI-1 || lane < (TPW*100 - 64*(NI-1)))
            gll16(fB + cur[m], (void*)&E[m*256]);
    }

    // read-slot offsets: logical chunk k lives at slot (k+gc)%5
    int koff[5];
    #pragma unroll
    for (int k = 0; k < 5; ++k){ int kp = k + (gc % 5); if (kp >= 5) kp -= 5; koff[k] = 4*kp; }
    const int rot = (p + gc) % 5;   // exp-pass row rotation (bank spread)

    float vA[20][4], vB[20][4];
    int cexp[4] = {0,0,0,0};
    #pragma unroll
    for (int j = 0; j < 20; ++j)
        #pragma unroll
        for (int cc = 0; cc < 4; ++cc) vA[j][cc] = (j == 4*p + cc) ? 1.f : 0.f;

    auto STEP = [&](float (&VIN)[20][4], float (&VOUT)[20][4], int it){
        asm volatile("s_waitcnt vmcnt(0)" ::: "memory");     // raw E_t landed
        // in-place exp2 of own 4 rows
        if (lane < 5*TPW){
            #pragma unroll
            for (int mm = 0; mm < 4; ++mm){
                int rr = 5*mm + rot;
                float* rp = &E[gc*NST + rr*20];
                #pragma unroll
                for (int k5 = 0; k5 < 5; ++k5){
                    float4 x = *(float4*)(rp + 4*k5);
                    x.x = fexp2(x.x*LOG2E); x.y = fexp2(x.y*LOG2E);
                    x.z = fexp2(x.z*LOG2E); x.w = fexp2(x.w*LOG2E);
                    *(float4*)(rp + 4*k5) = x;
                }
            }
        }
        asm volatile("s_waitcnt lgkmcnt(0)" ::: "memory");   // exp writes visible
        #pragma unroll
        for (int ii = 0; ii < 20; ++ii){
            const float* rb = &E[gc*NST + ii*20];
            float4 e0 = *(const float4*)(rb + koff[0]);
            float4 e1 = *(const float4*)(rb + koff[1]);
            float4 e2 = *(const float4*)(rb + koff[2]);
            float4 e3 = *(const float4*)(rb + koff[3]);
            float4 e4 = *(const float4*)(rb + koff[4]);
            #pragma unroll
            for (int cc = 0; cc < 4; ++cc){
                float s0 = e0.x*VIN[0][cc];
                float s1 = e0.y*VIN[1][cc];
                s0 = fmaf(e0.z, VIN[2][cc],  s0);  s1 = fmaf(e0.w, VIN[3][cc],  s1);
                s0 = fmaf(e1.x, VIN[4][cc],  s0);  s1 = fmaf(e1.y, VIN[5][cc],  s1);
                s0 = fmaf(e1.z, VIN[6][cc],  s0);  s1 = fmaf(e1.w, VIN[7][cc],  s1);
                s0 = fmaf(e2.x, VIN[8][cc],  s0);  s1 = fmaf(e2.y, VIN[9][cc],  s1);
                s0 = fmaf(e2.z, VIN[10][cc], s0);  s1 = fmaf(e2.w, VIN[11][cc], s1);
                s0 = fmaf(e3.x, VIN[12][cc], s0);  s1 = fmaf(e3.y, VIN[13][cc], s1);
                s0 = fmaf(e3.z, VIN[14][cc], s0);  s1 = fmaf(e3.w, VIN[15][cc], s1);
                s0 = fmaf(e4.x, VIN[16][cc], s0);  s1 = fmaf(e4.y, VIN[17][cc], s1);
                s0 = fmaf(e4.z, VIN[18][cc], s0);  s1 = fmaf(e4.w, VIN[19][cc], s1);
                VOUT[ii][cc] = s0 + s1;
            }
        }
        const bool ok = (it < nv_);                          // freeze finished tasks
        #pragma unroll
        for (int j = 0; j < 20; ++j)
            #pragma unroll
            for (int cc = 0; cc < 4; ++cc) VOUT[j][cc] = ok ? VOUT[j][cc] : VIN[j][cc];
        if ((it & 3) == 3){                                  // exact pow2 renorm
            #pragma unroll
            for (int cc = 0; cc < 4; ++cc){
                float mx = VOUT[0][cc];
                #pragma unroll
                for (int j = 1; j < 20; ++j) mx = fmaxf(mx, VOUT[j][cc]);
                int e = (int)((__float_as_uint(mx) >> 23) & 255) - 127;
                float sc = __uint_as_float((uint32_t)(127 - e) << 23);
                #pragma unroll
                for (int j = 0; j < 20; ++j) VOUT[j][cc] *= sc;
                cexp[cc] += e;
            }
        }
        asm volatile("s_waitcnt lgkmcnt(0)" ::: "memory");   // all E reads retired
        if (it + 1 < itmax){                                 // DMA next step (single buffer)
            #pragma unroll
            for (int m = 0; m < NI; ++m){
                uint32_t nx = cur[m] + 1600u;
                cur[m] = nx > lim[m] ? lim[m] : nx;
                if (m < NI-1 || lane < (TPW*100 - 64*(NI-1)))
                    gll16(fB + cur[m], (void*)&E[m*256]);
            }
        }
    };

    int it = 0;
    while (true){
        STEP(vA, vB, it); ++it;
        if (it >= itmax){
            #pragma unroll
            for (int j = 0; j < 20; ++j)
                #pragma unroll
                for (int cc = 0; cc < 4; ++cc) vA[j][cc] = vB[j][cc];
            break;
        }
        STEP(vB, vA, it); ++it;
        if (it >= itmax) break;
    }

    if (real && nv_ > 0){
        float* out = wseg + (size_t)task * SEGSTRIDE;
        #pragma unroll
        for (int ii = 0; ii < 20; ++ii)
            *(float4*)&out[ii*20 + 4*p] = make_float4(vA[ii][0], vA[ii][1], vA[ii][2], vA[ii][3]);
        int* oi = (int*)out;
        #pragma unroll
        for (int cc = 0; cc < 4; ++cc) oi[NST + 4*p + cc] = cexp[cc];
    }
}

// ============ pass 2: serial segment applications (<=SEGS steps) ============
template<int SEGL, int SEGS>
__global__ __launch_bounds__(64,1) void chain_kernel2(
    const float* __restrict__ feats, const float* __restrict__ trans,
    const int* __restrict__ targets, const int* __restrict__ lengths,
    const float* __restrict__ wseg, float* __restrict__ partialA)
{
    constexpr float LOG2E = 1.4426950408889634f;
    constexpr float LN2   = 0.6931471805599453f;
    const int b = blockIdx.x;
    const int lane = threadIdx.x;
    const int len = lengths[b];
    const bool act = lane < KK;
    const int li = act ? lane : 0;

    __shared__ __align__(16) float Ul[KK];

    const float* fb = feats + (size_t)b*TT*NST;
    float a2 = fb[li*KK + START_TAG] * LOG2E;
    float c0 = __builtin_amdgcn_readfirstlane(__float_as_uint(a2)) ?
               __uint_as_float(__builtin_amdgcn_readfirstlane(__float_as_uint(a2))) : 0.f;
    c0 = __uint_as_float(__builtin_amdgcn_readfirstlane(__float_as_uint(a2)));
    float CW = c0;
    float wk = act ? fexp2(a2 - c0) : 0.f;

    const int nseg = (len - 1 + SEGL - 1) / SEGL;

    if (act && nseg > 0){
        float4 mA[5], mB[5];
        int cA = 0, cB = 0;
        auto LDM = [&](int s2, float4 (&m)[5], int& c){
            const float* base = wseg + (size_t)(b*SEGS + s2)*SEGSTRIDE;
            const float4* p4 = (const float4*)(base + li*KK);
            m[0]=p4[0]; m[1]=p4[1]; m[2]=p4[2]; m[3]=p4[3]; m[4]=p4[4];
            c = ((const int*)base)[NST + li];
        };
        auto STEP = [&](float4 (&m)[5], int c){
            int e = (int)((__float_as_uint(wk) >> 23) & 255) - 127;
            int q = __builtin_amdgcn_readfirstlane(c + e);   // approx-max exponent (safe: spread << 60)
            Ul[li] = ldexpf(wk, c - q);
            asm volatile("s_waitcnt lgkmcnt(0)" ::: "memory");
            const float4* up = (const float4*)Ul;
            float4 u0 = up[0], u1 = up[1], u2 = up[2], u3 = up[3], u4 = up[4];
            float s0 = m[0].x*u0.x, s1 = m[0].y*u0.y;
            s0 = fmaf(m[0].z,u0.z,s0); s1 = fmaf(m[0].w,u0.w,s1);
            s0 = fmaf(m[1].x,u1.x,s0); s1 = fmaf(m[1].y,u1.y,s1);
            s0 = fmaf(m[1].z,u1.z,s0); s1 = fmaf(m[1].w,u1.w,s1);
            s0 = fmaf(m[2].x,u2.x,s0); s1 = fmaf(m[2].y,u2.y,s1);
            s0 = fmaf(m[2].z,u2.z,s0); s1 = fmaf(m[2].w,u2.w,s1);
            s0 = fmaf(m[3].x,u3.x,s0); s1 = fmaf(m[3].y,u3.y,s1);
            s0 = fmaf(m[3].z,u3.z,s0); s1 = fmaf(m[3].w,u3.w,s1);
            s0 = fmaf(m[4].x,u4.x,s0); s1 = fmaf(m[4].y,u4.y,s1);
            s0 = fmaf(m[4].z,u4.z,s0); s1 = fmaf(m[4].w,u4.w,s1);
            wk = s0 + s1;
            CW += (float)q;
            asm volatile("s_waitcnt lgkmcnt(0)" ::: "memory"); // Ul reads done before next write
        };
        LDM(0, mA, cA);
        for (int s2 = 0; s2 < nseg; ){
            if (s2 + 1 < nseg) LDM(s2 + 1, mB, cB);
            STEP(mA, cA);
            ++s2; if (s2 >= nseg) break;
            if (s2 + 1 < nseg) LDM(s2 + 1, mA, cA);
            STEP(mB, cB);
            ++s2;
        }
    }

    float term = act ? wk * fexp2(trans[STOP_TAG*KK + li] * LOG2E) : 0.f;
    #pragma unroll
    for (int o = 32; o > 0; o >>= 1) term += __shfl_xor(term, o, 64);
    if (lane == 0){
        float lse = LN2 * (CW + flog2(term));
        int last = targets[b*TT + len - 1];
        partialA[b] = lse - trans[STOP_TAG*KK + last];
    }
}

// ============ fallback: proven R1 serial forward ============
__global__ __launch_bounds__(64,1) void fwd_serial(
    const float* __restrict__ feats, const float* __restrict__ trans,
    const int* __restrict__ targets, const int* __restrict__ lengths,
    float* __restrict__ partialA)
{
    constexpr float LOG2E = 1.4426950408889634f;
    constexpr float LN2   = 0.6931471805599453f;
    const int b    = blockIdx.x;
    const int lane = threadIdx.x;
    const int len  = lengths[b];
    const float* fb = feats + (size_t)b * TT * NST;
    __shared__ __align__(16) float alpha[KK];
    __shared__ __align__(16) float xs[KK];
    const bool act = lane < KK;
    const int  li  = act ? lane : 0;
    if (act) alpha[lane] = fb[lane * KK + START_TAG] * LOG2E;
    __syncthreads();
    float4 b0[5], b1[5], b2[5], b3[5];
    auto LOAD = [&](float4* dst, int t){
        int tc = (t < len) ? t : (len - 1);
        const float4* p = (const float4*)(fb + (size_t)tc * NST + li * KK);
        dst[0]=p[0]; dst[1]=p[1]; dst[2]=p[2]; dst[3]=p[3]; dst[4]=p[4];
    };
    auto STEP = [&](const float4* bufv){
        const float4* ap = (const float4*)alpha;
        float a[KK];
        #pragma unroll
        for (int q = 0; q < 5; ++q){
            float4 av = ap[q];
            a[4*q+0]=av.x; a[4*q+1]=av.y; a[4*q+2]=av.z; a[4*q+3]=av.w;
        }
        float v[KK];
        #pragma unroll
        for (int q = 0; q < 5; ++q){
            v[4*q+0] = bufv[q].x * LOG2E + a[4*q+0];
            v[4*q+1] = bufv[q].y * LOG2E + a[4*q+1];
            v[4*q+2] = bufv[q].z * LOG2E + a[4*q+2];
            v[4*q+3] = bufv[q].w * LOG2E + a[4*q+3];
        }
        float m = v[0];
        #pragma unroll
        for (int j = 1; j < KK; ++j) m = fmaxf(m, v[j]);
        float s = 0.f;
        #pragma unroll
        for (int j = 0; j < KK; ++j) s += fexp2(v[j] - m);
        float na = m + flog2(s);
        __syncthreads();
        if (act) alpha[lane] = na;
        __syncthreads();
    };
    LOAD(b0,1); LOAD(b1,2); LOAD(b2,3); LOAD(b3,4);
    int t = 1;
    while (t < len){
        STEP(b0); LOAD(b0, t+4); ++t; if (t >= len) break;
        STEP(b1); LOAD(b1, t+4); ++t; if (t >= len) break;
        STEP(b2); LOAD(b2, t+4); ++t; if (t >= len) break;
        STEP(b3); LOAD(b3, t+4); ++t;
    }
    if (act) xs[lane] = alpha[lane] + trans[STOP_TAG*KK + lane] * LOG2E;
    __syncthreads();
    if (lane == 0){
        float m = xs[0];
        for (int j = 1; j < KK; ++j) m = fmaxf(m, xs[j]);
        float s = 0.f;
        for (int j = 0; j < KK; ++j) s += fexp2(xs[j] - m);
        float lse = LN2 * (m + flog2(s));
        int last_tag = targets[b*TT + (len-1)];
        partialA[b] = lse - trans[STOP_TAG*KK + last_tag];
    }
}

// ============ gold path + final reduce (proven) ============
__global__ __launch_bounds__(256) void gold_kernel(
    const float* __restrict__ feats, const int* __restrict__ targets,
    const int* __restrict__ lengths, float* __restrict__ partialG)
{
    const int b   = blockIdx.x;
    const int tt  = blockIdx.y * 256 + threadIdx.x;
    const int len = lengths[b];
    float val = 0.f;
    if (tt < len){
        int tgt  = targets[b*TT + tt];
        int prev = (tt > 0) ? targets[b*TT + tt - 1] : START_TAG;
        val = feats[((size_t)b*TT + tt)*NST + tgt*KK + prev];
    }
    #pragma unroll
    for (int off = 32; off > 0; off >>= 1) val += __shfl_down(val, off);
    __shared__ float wsum[4];
    if ((threadIdx.x & 63) == 0) wsum[threadIdx.x >> 6] = val;
    __syncthreads();
    if (threadIdx.x == 0)
        partialG[b*gridDim.y + blockIdx.y] = wsum[0]+wsum[1]+wsum[2]+wsum[3];
}

__global__ __launch_bounds__(256) void final_kernel(
    const float* __restrict__ partialA, const float* __restrict__ partialG,
    float* __restrict__ out)
{
    int tid = threadIdx.x;
    float v = partialA[tid] - partialG[tid] - partialG[tid + 256];
    #pragma unroll
    for (int off = 32; off > 0; off >>= 1) v += __shfl_down(v, off);
    __shared__ float wsum[4];
    if ((tid & 63) == 0) wsum[tid >> 6] = v;
    __syncthreads();
    if (tid == 0) out[0] = wsum[0]+wsum[1]+wsum[2]+wsum[3];
}

extern "C" void kernel_launch(void* const* d_in, const int* in_sizes, int n_in,
                              void* d_out, int out_size, void* d_ws, size_t ws_size,
                              hipStream_t stream) {
    const float* feats   = (const float*)d_in[0];
    const float* trans   = (const float*)d_in[1];
    const int*   targets = (const int*)d_in[2];
    const int*   lengths = (const int*)d_in[3];

    float* ws       = (float*)d_ws;
    float* partialA = ws;          // 256 floats
    float* partialG = ws + 256;    // 512 floats
    float* wseg     = ws + WS_SEG_OFF;

    const size_t need8  = (size_t)(WS_SEG_OFF + (size_t)BB*64*SEGSTRIDE) * sizeof(float);
    const size_t need16 = (size_t)(WS_SEG_OFF + (size_t)BB*32*SEGSTRIDE) * sizeof(float);

    if (ws_size >= need8){
        seg_kernel2<8,64><<<dim3((BB*64 + TPW-1)/TPW), dim3(64), 0, stream>>>(feats, lengths, wseg);
        chain_kernel2<8,64><<<dim3(BB), dim3(64), 0, stream>>>(feats, trans, targets, lengths, wseg, partialA);
    } else if (ws_size >= need16){
        seg_kernel2<16,32><<<dim3((BB*32 + TPW-1)/TPW), dim3(64), 0, stream>>>(feats, lengths, wseg);
        chain_kernel2<16,32><<<dim3(BB), dim3(64), 0, stream>>>(feats, trans, targets, lengths, wseg, partialA);
    } else {
        fwd_serial<<<dim3(BB), dim3(64), 0, stream>>>(feats, trans, targets, lengths, partialA);
    }
    gold_kernel<<<dim3(BB, 2), dim3(256), 0, stream>>>(feats, targets, lengths, partialG);
    final_kernel<<<dim3(1), dim3(256), 0, stream>>>(partialA, partialG, (float*)d_out);
}